// Round 6
// baseline (815.900 us; speedup 1.0000x reference)
//
#include <hip/hip_runtime.h>
#include <hip/hip_fp16.h>
#include <hip/hip_cooperative_groups.h>
#include <cstdint>

namespace cg = cooperative_groups;

#define BB 4
#define TT 12
#define NN 1000
#define FF 64
#define OO 64
#define SS 4096
#define G3 12288

typedef _Float16 f16x8 __attribute__((ext_vector_type(8)));
typedef float f32x4 __attribute__((ext_vector_type(4)));
typedef _Float16 h2v __attribute__((ext_vector_type(2)));

#if __has_builtin(__builtin_amdgcn_fdot2)
__device__ inline float fdot2(__half2 a, __half2 b, float c) {
    return __builtin_amdgcn_fdot2(*(h2v*)&a, *(h2v*)&b, c, false);
}
#else
__device__ inline float fdot2(__half2 a, __half2 b, float c) {
    float2 fa = __half22float2(a), fb = __half22float2(b);
    return fmaf(fa.x, fb.x, fmaf(fa.y, fb.y, c));
}
#endif

// ---------------------------------------------------------------- init h0 (fp32 + fp16 mirror)
__global__ void k_init_h(const float* __restrict__ h0, float* __restrict__ h_all,
                         __half* __restrict__ h16) {
    int i = blockIdx.x * 256 + threadIdx.x;
    if (i < BB * SS) {
        float v = h0[i & (SS - 1)];
        h_all[i] = v;
        h16[i] = __float2half(v);
    }
}

// ---------------------------------------------------------------- w_hh fp32 -> fp16 (fallback path only)
__global__ void k_conv(const float* __restrict__ w, __half* __restrict__ wh) {
    size_t i = ((size_t)blockIdx.x * 256 + threadIdx.x) * 8;
    float4 a = *(const float4*)(w + i);
    float4 b = *(const float4*)(w + i + 4);
    __half2 h0 = __floats2half2_rn(a.x, a.y);
    __half2 h1 = __floats2half2_rn(a.z, a.w);
    __half2 h2 = __floats2half2_rn(b.x, b.y);
    __half2 h3 = __floats2half2_rn(b.z, b.w);
    uint4 o;
    o.x = *(const unsigned*)&h0; o.y = *(const unsigned*)&h1;
    o.z = *(const unsigned*)&h2; o.w = *(const unsigned*)&h3;
    *(uint4*)(wh + i) = o;
}

// ---------------------------------------------------------------- summary = mean_n x
__global__ void k_summary(const float* __restrict__ x, float* __restrict__ summ) {
    int bt = blockIdx.x;
    int f = threadIdx.x & 63, part = threadIdx.x >> 6;
    const float* xp = x + (size_t)bt * NN * FF;
    float s = 0.f;
    for (int n = part; n < NN; n += 4) s += xp[(size_t)n * FF + f];
    __shared__ float red[4][64];
    red[part][f] = s;
    __syncthreads();
    if (part == 0) {
        float tot = red[0][f] + red[1][f] + red[2][f] + red[3][f];
        summ[bt * FF + f] = tot * (1.0f / NN);
    }
}

// ---------------------------------------------------------------- gi = summary @ w_ih^T + b_ih
__global__ void k_gi(const float* __restrict__ summ, const float* __restrict__ w_ih,
                     const float* __restrict__ b_ih, float* __restrict__ gi) {
    int bt = blockIdx.y;
    int j = blockIdx.x * 256 + threadIdx.x;
    __shared__ float sl[64];
    if (threadIdx.x < 64) sl[threadIdx.x] = summ[bt * 64 + threadIdx.x];
    __syncthreads();
    const float* wr = w_ih + (size_t)j * 64;
    float acc = b_ih[j];
#pragma unroll
    for (int k = 0; k < 64; k += 4) {
        float4 w4 = *(const float4*)(wr + k);
        acc += sl[k] * w4.x + sl[k + 1] * w4.y + sl[k + 2] * w4.z + sl[k + 3] * w4.w;
    }
    gi[(size_t)bt * G3 + j] = acc;
}

// ---------------------------------------------------------------- deg only (tier B/C)
__global__ void k_deg(const float* __restrict__ adj, float* __restrict__ invs) {
    int row = blockIdx.x * 4 + (threadIdx.x >> 6);
    int lane = threadIdx.x & 63;
    const float* a = adj + (size_t)row * NN;
    float s = 0.f;
    for (int m = lane * 4; m < NN; m += 256) {
        float4 v = *(const float4*)(a + m);
        s += v.x + v.y + v.z + v.w;
    }
#pragma unroll
    for (int off = 32; off; off >>= 1) s += __shfl_down(s, off);
    if (lane == 0) invs[row] = rsqrtf(fmaxf(s + 1.0f, 1e-8f));
}

// ---------------------------------------------------------------- fused: deg + adj fp32->fp16 (tier A)
__global__ void k_degconv(const float* __restrict__ adj, float* __restrict__ invs,
                          __half* __restrict__ adjh) {
    int row = blockIdx.x * 4 + (threadIdx.x >> 6);   // 48000 rows
    int lane = threadIdx.x & 63;
    const float* a = adj + (size_t)row * NN;
    __half* oh = adjh + (size_t)row * NN;
    float s = 0.f;
    for (int m4 = lane; m4 < 250; m4 += 64) {        // float4 index, NN/4 = 250
        float4 v = *(const float4*)(a + m4 * 4);
        s += v.x + v.y + v.z + v.w;
        __half2 p0 = __floats2half2_rn(v.x, v.y);
        __half2 p1 = __floats2half2_rn(v.z, v.w);
        uint2 pk;
        pk.x = *(const unsigned*)&p0; pk.y = *(const unsigned*)&p1;
        *(uint2*)(oh + m4 * 4) = pk;
    }
#pragma unroll
    for (int off = 32; off; off >>= 1) s += __shfl_down(s, off);
    if (lane == 0) invs[row] = rsqrtf(fmaxf(s + 1.0f, 1e-8f));
}

// ---------------------------------------------------------------- persistent GRU: all 12 steps, 1 cooperative launch
// 256 blocks x 1024 thr (1 block/CU). Wave w owns gate row jg = blk*16+w (3 parts, 4 batches).
// t==0: reads fp32 w_hh, converts+writes wh (fuses k_conv). t>0: reads fp16 wh (L3-hot).
// h16 staged in LDS once per block per step; grid.sync() between steps.
__global__ __launch_bounds__(1024, 4) void k_gru_all(const float* __restrict__ w32,
                                                     __half* __restrict__ wh,
                                                     const float* __restrict__ b_hh,
                                                     const float* __restrict__ gi,
                                                     float* __restrict__ h_all,
                                                     __half* __restrict__ h16) {
    cg::grid_group grid = cg::this_grid();
    __shared__ __half hl[BB * SS];                   // 32 KB
    int wave = threadIdx.x >> 6, lane = threadIdx.x & 63;
    int jg = blockIdx.x * 16 + wave;                 // 0..4095
    const size_t row0 = (size_t)jg * SS;
    const size_t row1 = ((size_t)SS + jg) * SS;
    const size_t row2 = ((size_t)2 * SS + jg) * SS;

    for (int t = 0; t < TT; ++t) {
        // stage h16[t] -> LDS (1024 thr x 16 halves)
        {
            const __half* hsrc = h16 + (size_t)t * BB * SS;
            int i = threadIdx.x * 16;
            uint4 a = *(const uint4*)(hsrc + i);
            uint4 b = *(const uint4*)(hsrc + i + 8);
            *(uint4*)(hl + i) = a;
            *(uint4*)(hl + i + 8) = b;
        }
        __syncthreads();

        float acc[3][4] = {{0.f}};
        if (t == 0) {
            // fp32 weights: convert, write wh, accumulate
            for (int k0 = 0; k0 < SS; k0 += 512) {
                int k = k0 + lane * 8;
                float4 a0 = *(const float4*)(w32 + row0 + k);
                float4 b0 = *(const float4*)(w32 + row0 + k + 4);
                float4 a1 = *(const float4*)(w32 + row1 + k);
                float4 b1 = *(const float4*)(w32 + row1 + k + 4);
                float4 a2 = *(const float4*)(w32 + row2 + k);
                float4 b2 = *(const float4*)(w32 + row2 + k + 4);
                __half2 w0[4] = {__floats2half2_rn(a0.x, a0.y), __floats2half2_rn(a0.z, a0.w),
                                 __floats2half2_rn(b0.x, b0.y), __floats2half2_rn(b0.z, b0.w)};
                __half2 w1[4] = {__floats2half2_rn(a1.x, a1.y), __floats2half2_rn(a1.z, a1.w),
                                 __floats2half2_rn(b1.x, b1.y), __floats2half2_rn(b1.z, b1.w)};
                __half2 w2[4] = {__floats2half2_rn(a2.x, a2.y), __floats2half2_rn(a2.z, a2.w),
                                 __floats2half2_rn(b2.x, b2.y), __floats2half2_rn(b2.z, b2.w)};
                *(uint4*)(wh + row0 + k) = *(const uint4*)w0;
                *(uint4*)(wh + row1 + k) = *(const uint4*)w1;
                *(uint4*)(wh + row2 + k) = *(const uint4*)w2;
#pragma unroll
                for (int b = 0; b < 4; ++b) {
                    uint4 hu = *(const uint4*)(hl + b * SS + k);
                    const __half2* hv = (const __half2*)&hu;
#pragma unroll
                    for (int q = 0; q < 4; ++q) {
                        acc[0][b] = fdot2(w0[q], hv[q], acc[0][b]);
                        acc[1][b] = fdot2(w1[q], hv[q], acc[1][b]);
                        acc[2][b] = fdot2(w2[q], hv[q], acc[2][b]);
                    }
                }
            }
        } else {
            // fp16 weights, unroll x2 for load MLP
            for (int k0 = 0; k0 < SS; k0 += 1024) {
                int ka = k0 + lane * 8;
                int kb = ka + 512;
                uint4 u0a = *(const uint4*)(wh + row0 + ka);
                uint4 u1a = *(const uint4*)(wh + row1 + ka);
                uint4 u2a = *(const uint4*)(wh + row2 + ka);
                uint4 u0b = *(const uint4*)(wh + row0 + kb);
                uint4 u1b = *(const uint4*)(wh + row1 + kb);
                uint4 u2b = *(const uint4*)(wh + row2 + kb);
                const __half2* w0a = (const __half2*)&u0a;
                const __half2* w1a = (const __half2*)&u1a;
                const __half2* w2a = (const __half2*)&u2a;
                const __half2* w0b = (const __half2*)&u0b;
                const __half2* w1b = (const __half2*)&u1b;
                const __half2* w2b = (const __half2*)&u2b;
#pragma unroll
                for (int b = 0; b < 4; ++b) {
                    uint4 hua = *(const uint4*)(hl + b * SS + ka);
                    uint4 hub = *(const uint4*)(hl + b * SS + kb);
                    const __half2* hva = (const __half2*)&hua;
                    const __half2* hvb = (const __half2*)&hub;
#pragma unroll
                    for (int q = 0; q < 4; ++q) {
                        acc[0][b] = fdot2(w0a[q], hva[q], acc[0][b]);
                        acc[1][b] = fdot2(w1a[q], hva[q], acc[1][b]);
                        acc[2][b] = fdot2(w2a[q], hva[q], acc[2][b]);
                        acc[0][b] = fdot2(w0b[q], hvb[q], acc[0][b]);
                        acc[1][b] = fdot2(w1b[q], hvb[q], acc[1][b]);
                        acc[2][b] = fdot2(w2b[q], hvb[q], acc[2][b]);
                    }
                }
            }
        }
#pragma unroll
        for (int p = 0; p < 3; ++p)
#pragma unroll
            for (int b = 0; b < 4; ++b)
#pragma unroll
                for (int off = 32; off; off >>= 1)
                    acc[p][b] += __shfl_down(acc[p][b], off);
        if (lane == 0) {
            float br = b_hh[jg], bz = b_hh[SS + jg], bn = b_hh[2 * SS + jg];
            const float* h_in = h_all + (size_t)t * BB * SS;
            float* h_out = h_all + (size_t)(t + 1) * BB * SS;
            __half* h16_out = h16 + (size_t)(t + 1) * BB * SS;
#pragma unroll
            for (int b = 0; b < 4; ++b) {
                const float* gib = gi + ((size_t)b * TT + t) * G3;
                float r = 1.f / (1.f + expf(-(gib[jg] + acc[0][b] + br)));
                float z = 1.f / (1.f + expf(-(gib[SS + jg] + acc[1][b] + bz)));
                float nn = tanhf(gib[2 * SS + jg] + r * (acc[2][b] + bn));
                float hv = (1.f - z) * nn + z * h_in[(size_t)b * SS + jg];
                h_out[(size_t)b * SS + jg] = hv;
                h16_out[(size_t)b * SS + jg] = __float2half(hv);
            }
        }
        grid.sync();
    }
}

// ---------------------------------------------------------------- GRU step: LDS-free (fallback, non-coop)
__global__ __launch_bounds__(256) void k_gru_h3(const __half* __restrict__ w_hh,
                                                const __half* __restrict__ h16_in,
                                                const float* __restrict__ h_in,
                                                const float* __restrict__ b_hh,
                                                const float* __restrict__ gi,
                                                float* __restrict__ h_out,
                                                __half* __restrict__ h16_out, int t) {
    int wave = threadIdx.x >> 6, lane = threadIdx.x & 63;
    int jg = blockIdx.x * 4 + wave;
    const __half* r0 = w_hh + (size_t)jg * SS;
    const __half* r1 = w_hh + ((size_t)SS + jg) * SS;
    const __half* r2 = w_hh + ((size_t)2 * SS + jg) * SS;
    float acc[3][4] = {{0.f}};
    for (int k0 = 0; k0 < SS; k0 += 512) {
        int k = k0 + lane * 8;
        uint4 u0 = *(const uint4*)(r0 + k);
        uint4 u1 = *(const uint4*)(r1 + k);
        uint4 u2 = *(const uint4*)(r2 + k);
        const __half2* w0 = (const __half2*)&u0;
        const __half2* w1 = (const __half2*)&u1;
        const __half2* w2 = (const __half2*)&u2;
#pragma unroll
        for (int b = 0; b < 4; ++b) {
            uint4 hu = *(const uint4*)(h16_in + (size_t)b * SS + k);
            const __half2* hv = (const __half2*)&hu;
#pragma unroll
            for (int q = 0; q < 4; ++q) {
                acc[0][b] = fdot2(w0[q], hv[q], acc[0][b]);
                acc[1][b] = fdot2(w1[q], hv[q], acc[1][b]);
                acc[2][b] = fdot2(w2[q], hv[q], acc[2][b]);
            }
        }
    }
#pragma unroll
    for (int p = 0; p < 3; ++p)
#pragma unroll
        for (int b = 0; b < 4; ++b)
#pragma unroll
            for (int off = 32; off; off >>= 1)
                acc[p][b] += __shfl_down(acc[p][b], off);
    if (lane == 0) {
        float br = b_hh[jg], bz = b_hh[SS + jg], bn = b_hh[2 * SS + jg];
#pragma unroll
        for (int b = 0; b < 4; ++b) {
            const float* gib = gi + ((size_t)b * TT + t) * G3;
            float r = 1.f / (1.f + expf(-(gib[jg] + acc[0][b] + br)));
            float z = 1.f / (1.f + expf(-(gib[SS + jg] + acc[1][b] + bz)));
            float nn = tanhf(gib[2 * SS + jg] + r * (acc[2][b] + bn));
            float hv = (1.f - z) * nn + z * h_in[(size_t)b * SS + jg];
            h_out[(size_t)b * SS + jg] = hv;
            h16_out[(size_t)b * SS + jg] = __float2half(hv);
        }
    }
}

// ---------------------------------------------------------------- GRU step fp32 (tier C fallback)
__global__ __launch_bounds__(512) void k_gru(const float* __restrict__ w_hh,
                                             const float* __restrict__ b_hh,
                                             const float* __restrict__ gi,
                                             const float* __restrict__ h_in,
                                             float* __restrict__ h_out, int t) {
    __shared__ float hl[BB][SS];
    for (int i = threadIdx.x; i < BB * SS; i += 512)
        hl[i >> 12][i & (SS - 1)] = h_in[i];
    __syncthreads();
    int wave = threadIdx.x >> 6, lane = threadIdx.x & 63;
    int jg = blockIdx.x * 8 + wave;
    const float* r0 = w_hh + (size_t)jg * SS;
    const float* r1 = w_hh + ((size_t)SS + jg) * SS;
    const float* r2 = w_hh + ((size_t)2 * SS + jg) * SS;
    float acc[3][4] = {{0.f}};
    for (int k0 = 0; k0 < SS; k0 += 256) {
        int k = k0 + lane * 4;
        float4 w0 = *(const float4*)(r0 + k);
        float4 w1 = *(const float4*)(r1 + k);
        float4 w2 = *(const float4*)(r2 + k);
#pragma unroll
        for (int b = 0; b < 4; ++b) {
            float4 hv = *(const float4*)&hl[b][k];
            acc[0][b] += w0.x * hv.x + w0.y * hv.y + w0.z * hv.z + w0.w * hv.w;
            acc[1][b] += w1.x * hv.x + w1.y * hv.y + w1.z * hv.z + w1.w * hv.w;
            acc[2][b] += w2.x * hv.x + w2.y * hv.y + w2.z * hv.z + w2.w * hv.w;
        }
    }
#pragma unroll
    for (int p = 0; p < 3; ++p)
#pragma unroll
        for (int b = 0; b < 4; ++b)
#pragma unroll
            for (int off = 32; off; off >>= 1)
                acc[p][b] += __shfl_down(acc[p][b], off);
    if (lane == 0) {
        float br = b_hh[jg], bz = b_hh[SS + jg], bn = b_hh[2 * SS + jg];
#pragma unroll
        for (int b = 0; b < 4; ++b) {
            const float* gib = gi + ((size_t)b * TT + t) * G3;
            float r = 1.f / (1.f + expf(-(gib[jg] + acc[0][b] + br)));
            float z = 1.f / (1.f + expf(-(gib[SS + jg] + acc[1][b] + bz)));
            float nn = tanhf(gib[2 * SS + jg] + r * (acc[2][b] + bn));
            h_out[(size_t)b * SS + jg] = (1.f - z) * nn + z * hl[b][jg];
        }
    }
}

// ---------------------------------------------------------------- support (tier A): sp fp32 + spT fp16 transposed
__global__ __launch_bounds__(256) void k_support2(const float* __restrict__ x,
                                                  const float* __restrict__ h_all,
                                                  const float* __restrict__ invs,
                                                  float* __restrict__ sp,
                                                  __half* __restrict__ spT) {
    int nt = blockIdx.x, b = blockIdx.y, t = blockIdx.z;
    int n0 = nt * 64;
    int o = threadIdx.x & 63, g = threadIdx.x >> 6;
    __shared__ float wl[64][64];
    __shared__ float xl[64][64];
    __shared__ __half tl[64][72];
    for (int i = threadIdx.x; i < 64 * 72 / 2; i += 256)
        *(__half2*)&tl[0][i * 2] = __half2{};
    const float* h = h_all + ((size_t)(t + 1) * BB + b) * SS;
    for (int i = threadIdx.x; i < SS; i += 256) wl[i >> 6][i & 63] = h[i];
    const float* xp = x + ((size_t)(b * TT + t) * NN + n0) * FF;
    for (int i = threadIdx.x; i < 64 * 64; i += 256) {
        int nl = i >> 6, f = i & 63;
        xl[nl][f] = (n0 + nl < NN) ? xp[(size_t)nl * FF + f] : 0.f;
    }
    __syncthreads();
    size_t bt = (size_t)b * TT + t;
    for (int nl = g; nl < 64; nl += 4) {
        int n = n0 + nl;
        if (n >= NN) break;
        float acc = 0.f;
#pragma unroll
        for (int f = 0; f < 64; ++f) acc += xl[nl][f] * wl[f][o];
        size_t idx = bt * NN + n;
        float v = acc * invs[idx];
        sp[idx * OO + o] = v;
        tl[o][nl] = __float2half(v);
    }
    __syncthreads();
    int orow = threadIdx.x >> 2, seg = threadIdx.x & 3;
    uint4 lo = *(const uint4*)&tl[orow][seg * 16];
    uint4 hi = *(const uint4*)&tl[orow][seg * 16 + 8];
    __half* dst = spT + ((bt * 64 + orow) * 1024 + n0 + seg * 16);
    *(uint4*)dst = lo;
    *(uint4*)(dst + 8) = hi;
}

// ---------------------------------------------------------------- support (tier B/C): sp fp32 only
__global__ __launch_bounds__(256) void k_support(const float* __restrict__ x,
                                                 const float* __restrict__ h_all,
                                                 const float* __restrict__ invs,
                                                 float* __restrict__ sp) {
    int nt = blockIdx.x, b = blockIdx.y, t = blockIdx.z;
    int n0 = nt * 64;
    int o = threadIdx.x & 63, g = threadIdx.x >> 6;
    __shared__ float wl[64][64];
    __shared__ float xl[64][64];
    const float* h = h_all + ((size_t)(t + 1) * BB + b) * SS;
    for (int i = threadIdx.x; i < SS; i += 256) wl[i >> 6][i & 63] = h[i];
    const float* xp = x + ((size_t)(b * TT + t) * NN + n0) * FF;
    for (int i = threadIdx.x; i < 64 * 64; i += 256) {
        int nl = i >> 6, f = i & 63;
        xl[nl][f] = (n0 + nl < NN) ? xp[(size_t)nl * FF + f] : 0.f;
    }
    __syncthreads();
    for (int nl = g; nl < 64; nl += 4) {
        int n = n0 + nl;
        if (n >= NN) break;
        float acc = 0.f;
#pragma unroll
        for (int f = 0; f < 64; ++f) acc += xl[nl][f] * wl[f][o];
        size_t idx = ((size_t)(b * TT + t) * NN + n);
        sp[idx * OO + o] = acc * invs[idx];
    }
}

// ---------------------------------------------------------------- k_out MFMA (tier A)
__global__ __launch_bounds__(256) void k_out_mfma(const __half* __restrict__ adjh,
                                                  const __half* __restrict__ spT,
                                                  const float* __restrict__ sp32,
                                                  const float* __restrict__ invs,
                                                  const float* __restrict__ bias,
                                                  float* __restrict__ out) {
    int nb = blockIdx.x, b = blockIdx.y, t = blockIdx.z;
    int n0 = nb * 64;
    size_t bt = (size_t)b * TT + t;
    __shared__ alignas(16) __half Al[64 * 64];
    __shared__ alignas(16) __half Bl[64 * 64];
    int wave = threadIdx.x >> 6, lane = threadIdx.x & 63;
    const __half* Ag = adjh + bt * (size_t)(NN * NN);
    const __half* Bg = spT + bt * (size_t)(64 * 1024);
    f32x4 acc[4] = {};

    for (int ch = 0; ch < 16; ++ch) {
        __syncthreads();
#pragma unroll
        for (int rep = 0; rep < 2; ++rep) {
            int idx = threadIdx.x + rep * 256;
            int r = idx >> 3, g = idx & 7;
            int gg = ch * 8 + g;
            uint4 va = {0, 0, 0, 0};
            if (n0 + r < NN && gg < 125)
                va = *(const uint4*)(Ag + (size_t)(n0 + r) * NN + gg * 8);
            *(uint4*)&Al[(r * 8 + (g ^ (r & 7))) * 8] = va;
            uint4 vb = *(const uint4*)(Bg + (size_t)r * 1024 + gg * 8);
            *(uint4*)&Bl[(r * 8 + (g ^ (r & 7))) * 8] = vb;
        }
        __syncthreads();
#pragma unroll
        for (int kc = 0; kc < 2; ++kc) {
            int ar = wave * 16 + (lane & 15);
            int ag = kc * 4 + (lane >> 4);
            f16x8 av = *(const f16x8*)&Al[(ar * 8 + (ag ^ (ar & 7))) * 8];
#pragma unroll
            for (int ct = 0; ct < 4; ++ct) {
                int br = ct * 16 + (lane & 15);
                f16x8 bv = *(const f16x8*)&Bl[(br * 8 + (ag ^ (br & 7))) * 8];
                acc[ct] = __builtin_amdgcn_mfma_f32_16x16x32_f16(av, bv, acc[ct], 0, 0, 0);
            }
        }
    }
#pragma unroll
    for (int ct = 0; ct < 4; ++ct) {
        int o = ct * 16 + (lane & 15);
        float bo = bias[o];
#pragma unroll
        for (int r = 0; r < 4; ++r) {
            int n = n0 + wave * 16 + (lane >> 4) * 4 + r;
            if (n < NN) {
                float iv = invs[bt * NN + n];
                float d = sp32[(bt * NN + n) * OO + o];
                out[(bt * NN + n) * OO + o] = fmaxf(iv * (acc[ct][r] + d) + bo, 0.f);
            }
        }
    }
}

// ---------------------------------------------------------------- k_out fp32 (tier B/C)
__global__ __launch_bounds__(256) void k_out(const float* __restrict__ adj,
                                             const float* __restrict__ sp,
                                             const float* __restrict__ invs,
                                             const float* __restrict__ bias,
                                             float* __restrict__ out) {
    int nb = blockIdx.x, b = blockIdx.y, t = blockIdx.z;
    int n0 = nb * 64;
    int cq = threadIdx.x & 15;
    int rg = threadIdx.x >> 4;
    __shared__ float spl[64][64];
    __shared__ float al[64][68];
    size_t bt = (size_t)b * TT + t;
    const float* adjp = adj + bt * (size_t)NN * NN;
    const float* spp  = sp  + bt * (size_t)NN * OO;
    float4 a0 = {0,0,0,0}, a1 = {0,0,0,0}, a2 = {0,0,0,0}, a3 = {0,0,0,0};
    for (int m0 = 0; m0 < NN; m0 += 64) {
        __syncthreads();
        for (int i = threadIdx.x; i < 1024; i += 256) {
            int r = i >> 4, c4 = (i & 15) * 4;
            int m = m0 + r;
            float4 v = (m < NN) ? *(const float4*)&spp[(size_t)m * OO + c4] : float4{0,0,0,0};
            *(float4*)&spl[r][c4] = v;
        }
        for (int i = threadIdx.x; i < 1024; i += 256) {
            int r = i >> 4, c4 = (i & 15) * 4;
            int n = n0 + r, m = m0 + c4;
            float4 v = (n < NN && m < NN) ? *(const float4*)&adjp[(size_t)n * NN + m] : float4{0,0,0,0};
            *(float4*)&al[r][c4] = v;
        }
        __syncthreads();
#pragma unroll 4
        for (int mm = 0; mm < 64; mm += 4) {
            float4 s0 = *(const float4*)&spl[mm + 0][cq * 4];
            float4 s1 = *(const float4*)&spl[mm + 1][cq * 4];
            float4 s2 = *(const float4*)&spl[mm + 2][cq * 4];
            float4 s3 = *(const float4*)&spl[mm + 3][cq * 4];
            float4 r0 = *(const float4*)&al[rg * 4 + 0][mm];
            float4 r1 = *(const float4*)&al[rg * 4 + 1][mm];
            float4 r2 = *(const float4*)&al[rg * 4 + 2][mm];
            float4 r3 = *(const float4*)&al[rg * 4 + 3][mm];
            a0.x += r0.x*s0.x + r0.y*s1.x + r0.z*s2.x + r0.w*s3.x;
            a0.y += r0.x*s0.y + r0.y*s1.y + r0.z*s2.y + r0.w*s3.y;
            a0.z += r0.x*s0.z + r0.y*s1.z + r0.z*s2.z + r0.w*s3.z;
            a0.w += r0.x*s0.w + r0.y*s1.w + r0.z*s2.w + r0.w*s3.w;
            a1.x += r1.x*s0.x + r1.y*s1.x + r1.z*s2.x + r1.w*s3.x;
            a1.y += r1.x*s0.y + r1.y*s1.y + r1.z*s2.y + r1.w*s3.y;
            a1.z += r1.x*s0.z + r1.y*s1.z + r1.z*s2.z + r1.w*s3.z;
            a1.w += r1.x*s0.w + r1.y*s1.w + r1.z*s2.w + r1.w*s3.w;
            a2.x += r2.x*s0.x + r2.y*s1.x + r2.z*s2.x + r2.w*s3.x;
            a2.y += r2.x*s0.y + r2.y*s1.y + r2.z*s2.y + r2.w*s3.y;
            a2.z += r2.x*s0.z + r2.y*s1.z + r2.z*s2.z + r2.w*s3.z;
            a2.w += r2.x*s0.w + r2.y*s1.w + r2.z*s2.w + r2.w*s3.w;
            a3.x += r3.x*s0.x + r3.y*s1.x + r3.z*s2.x + r3.w*s3.x;
            a3.y += r3.x*s0.y + r3.y*s1.y + r3.z*s2.y + r3.w*s3.y;
            a3.z += r3.x*s0.z + r3.y*s1.z + r3.z*s2.z + r3.w*s3.z;
            a3.w += r3.x*s0.w + r3.y*s1.w + r3.w*s3.w + r3.z*s2.w;
        }
    }
    float4 bias4 = *(const float4*)&bias[cq * 4];
    float4 accs[4] = {a0, a1, a2, a3};
#pragma unroll
    for (int i = 0; i < 4; ++i) {
        int n = n0 + rg * 4 + i;
        if (n < NN) {
            float iv = invs[bt * NN + n];
            float4 d = *(const float4*)&spp[(size_t)n * OO + cq * 4];
            float4 v;
            v.x = fmaxf(iv * (accs[i].x + d.x) + bias4.x, 0.f);
            v.y = fmaxf(iv * (accs[i].y + d.y) + bias4.y, 0.f);
            v.z = fmaxf(iv * (accs[i].z + d.z) + bias4.z, 0.f);
            v.w = fmaxf(iv * (accs[i].w + d.w) + bias4.w, 0.f);
            *(float4*)&out[(bt * NN + n) * OO + cq * 4] = v;
        }
    }
}

// ---------------------------------------------------------------- launch
extern "C" void kernel_launch(void* const* d_in, const int* in_sizes, int n_in,
                              void* d_out, int out_size, void* d_ws, size_t ws_size,
                              hipStream_t stream) {
    const float* x    = (const float*)d_in[0];
    const float* adj  = (const float*)d_in[1];
    const float* w_ih = (const float*)d_in[2];
    const float* w_hh = (const float*)d_in[3];
    const float* b_ih = (const float*)d_in[4];
    const float* b_hh = (const float*)d_in[5];
    const float* h0   = (const float*)d_in[6];
    const float* bias = (const float*)d_in[7];
    float* out = (float*)d_out;
    float* ws = (float*)d_ws;

    float* invs  = ws;                          // 48000
    float* summ  = invs + 48000;                // 3072
    float* gi    = summ + 3072;                 // 589824
    float* h_all = gi + 589824;                 // 13 * 16384 = 212992
    float* sp    = h_all + 212992;              // 3072000
    const size_t base_f = 3925888;              // floats
    __half* wh    = (__half*)(ws + base_f);         // 50,331,648 halves (100.7 MB)
    __half* h16   = wh + 50331648ull;               // 13 * 16384 halves
    __half* adjh  = h16 + 212992ull;                // 48,000,000 halves (96 MB)
    __half* spT   = adjh + 48000000ull;             // 3,145,728 halves (6.3 MB)
    const size_t need_B = base_f * 4 + (50331648ull + 212992ull) * 2;
    const size_t need_A = need_B + (48000000ull + 3145728ull) * 2;
    bool tierA = ws_size >= need_A;
    bool tierB = ws_size >= need_B;

    int dev = 0, coop = 0;
    hipGetDevice(&dev);
    hipDeviceGetAttribute(&coop, hipDeviceAttributeCooperativeLaunch, dev);

    k_init_h<<<64, 256, 0, stream>>>(h0, h_all, h16);
    k_summary<<<48, 256, 0, stream>>>(x, summ);
    k_gi<<<dim3(48, 48), 256, 0, stream>>>(summ, w_ih, b_ih, gi);
    if (tierB && coop) {
        void* args[] = {(void*)&w_hh, (void*)&wh, (void*)&b_hh, (void*)&gi,
                        (void*)&h_all, (void*)&h16};
        hipLaunchCooperativeKernel((void*)k_gru_all, dim3(256), dim3(1024),
                                   args, 0, stream);
    } else if (tierB) {
        k_conv<<<24576, 256, 0, stream>>>(w_hh, wh);
        for (int t = 0; t < TT; ++t)
            k_gru_h3<<<1024, 256, 0, stream>>>(wh,
                                               h16 + (size_t)t * BB * SS,
                                               h_all + (size_t)t * BB * SS,
                                               b_hh, gi,
                                               h_all + (size_t)(t + 1) * BB * SS,
                                               h16 + (size_t)(t + 1) * BB * SS, t);
    } else {
        for (int t = 0; t < TT; ++t)
            k_gru<<<512, 512, 0, stream>>>(w_hh, b_hh, gi,
                                           h_all + (size_t)t * BB * SS,
                                           h_all + (size_t)(t + 1) * BB * SS, t);
    }
    if (tierA) {
        k_degconv<<<12000, 256, 0, stream>>>(adj, invs, adjh);
        k_support2<<<dim3(16, 4, 12), 256, 0, stream>>>(x, h_all, invs, sp, spT);
        k_out_mfma<<<dim3(16, 4, 12), 256, 0, stream>>>(adjh, spT, sp, invs, bias, out);
    } else {
        k_deg<<<12000, 256, 0, stream>>>(adj, invs);
        k_support<<<dim3(16, 4, 12), 256, 0, stream>>>(x, h_all, invs, sp);
        k_out<<<dim3(16, 4, 12), 256, 0, stream>>>(adj, sp, invs, bias, out);
    }
}

// Round 7
// 496.661 us; speedup vs baseline: 1.6428x; 1.6428x over previous
//
#include <hip/hip_runtime.h>
#include <hip/hip_fp16.h>
#include <cstdint>

#define BB 4
#define TT 12
#define NN 1000
#define FF 64
#define OO 64
#define SS 4096
#define G3 12288

typedef _Float16 f16x8 __attribute__((ext_vector_type(8)));
typedef float f32x4 __attribute__((ext_vector_type(4)));
typedef _Float16 h2v __attribute__((ext_vector_type(2)));

#if __has_builtin(__builtin_amdgcn_fdot2)
__device__ inline float fdot2(__half2 a, __half2 b, float c) {
    return __builtin_amdgcn_fdot2(*(h2v*)&a, *(h2v*)&b, c, false);
}
#else
__device__ inline float fdot2(__half2 a, __half2 b, float c) {
    float2 fa = __half22float2(a), fb = __half22float2(b);
    return fmaf(fa.x, fb.x, fmaf(fa.y, fb.y, c));
}
#endif

// ---------------------------------------------------------------- init h0 (fp32 + fp16 mirror)
__global__ void k_init_h(const float* __restrict__ h0, float* __restrict__ h_all,
                         __half* __restrict__ h16) {
    int i = blockIdx.x * 256 + threadIdx.x;
    if (i < BB * SS) {
        float v = h0[i & (SS - 1)];
        h_all[i] = v;
        h16[i] = __float2half(v);
    }
}

// ---------------------------------------------------------------- summary = mean_n x
__global__ void k_summary(const float* __restrict__ x, float* __restrict__ summ) {
    int bt = blockIdx.x;
    int f = threadIdx.x & 63, part = threadIdx.x >> 6;
    const float* xp = x + (size_t)bt * NN * FF;
    float s = 0.f;
    for (int n = part; n < NN; n += 4) s += xp[(size_t)n * FF + f];
    __shared__ float red[4][64];
    red[part][f] = s;
    __syncthreads();
    if (part == 0) {
        float tot = red[0][f] + red[1][f] + red[2][f] + red[3][f];
        summ[bt * FF + f] = tot * (1.0f / NN);
    }
}

// ---------------------------------------------------------------- gi = summary @ w_ih^T + b_ih
__global__ void k_gi(const float* __restrict__ summ, const float* __restrict__ w_ih,
                     const float* __restrict__ b_ih, float* __restrict__ gi) {
    int bt = blockIdx.y;
    int j = blockIdx.x * 256 + threadIdx.x;
    __shared__ float sl[64];
    if (threadIdx.x < 64) sl[threadIdx.x] = summ[bt * 64 + threadIdx.x];
    __syncthreads();
    const float* wr = w_ih + (size_t)j * 64;
    float acc = b_ih[j];
#pragma unroll
    for (int k = 0; k < 64; k += 4) {
        float4 w4 = *(const float4*)(wr + k);
        acc += sl[k] * w4.x + sl[k + 1] * w4.y + sl[k + 2] * w4.z + sl[k + 3] * w4.w;
    }
    gi[(size_t)bt * G3 + j] = acc;
}

// ---------------------------------------------------------------- deg only (tier B/C)
__global__ void k_deg(const float* __restrict__ adj, float* __restrict__ invs) {
    int row = blockIdx.x * 4 + (threadIdx.x >> 6);
    int lane = threadIdx.x & 63;
    const float* a = adj + (size_t)row * NN;
    float s = 0.f;
    for (int m = lane * 4; m < NN; m += 256) {
        float4 v = *(const float4*)(a + m);
        s += v.x + v.y + v.z + v.w;
    }
#pragma unroll
    for (int off = 32; off; off >>= 1) s += __shfl_down(s, off);
    if (lane == 0) invs[row] = rsqrtf(fmaxf(s + 1.0f, 1e-8f));
}

// ---------------------------------------------------------------- fused: deg + adj fp32->fp16 (tier A)
__global__ void k_degconv(const float* __restrict__ adj, float* __restrict__ invs,
                          __half* __restrict__ adjh) {
    int row = blockIdx.x * 4 + (threadIdx.x >> 6);   // 48000 rows
    int lane = threadIdx.x & 63;
    const float* a = adj + (size_t)row * NN;
    __half* oh = adjh + (size_t)row * NN;
    float s = 0.f;
    for (int m4 = lane; m4 < 250; m4 += 64) {
        float4 v = *(const float4*)(a + m4 * 4);
        s += v.x + v.y + v.z + v.w;
        __half2 p0 = __floats2half2_rn(v.x, v.y);
        __half2 p1 = __floats2half2_rn(v.z, v.w);
        uint2 pk;
        pk.x = *(const unsigned*)&p0; pk.y = *(const unsigned*)&p1;
        *(uint2*)(oh + m4 * 4) = pk;
    }
#pragma unroll
    for (int off = 32; off; off >>= 1) s += __shfl_down(s, off);
    if (lane == 0) invs[row] = rsqrtf(fmaxf(s + 1.0f, 1e-8f));
}

// ---------------------------------------------------------------- GRU step, fine-grained: one wave per (gate,part) row
// 2048 blocks x 384 thr (6 waves = 2 gates x 3 parts). h16[t] staged in LDS (32 KB).
// Per wave: 8 chunks of {1 global uint4 weight + 4 LDS b128 h + 16 fdot2}.
// Cross-wave combine via sm[6][4]. 12288 waves total -> ~30 resident waves/CU.
__global__ __launch_bounds__(384) void k_gruN(const __half* __restrict__ wh,
                                              const __half* __restrict__ h16_in,
                                              const float* __restrict__ h_in,
                                              const float* __restrict__ b_hh,
                                              const float* __restrict__ gi,
                                              float* __restrict__ h_out,
                                              __half* __restrict__ h16_out, int t) {
    __shared__ __half hl[BB * SS];                   // 32 KB
    __shared__ float sm[6][4];
    for (int i = threadIdx.x; i < 2048; i += 384)
        *(uint4*)(hl + i * 8) = *(const uint4*)(h16_in + i * 8);
    __syncthreads();

    int w = threadIdx.x >> 6, lane = threadIdx.x & 63;
    int g = (w * 11) >> 5;                           // w/3 for w in [0,6)
    int p = w - g * 3;
    int j = blockIdx.x * 2 + g;
    const __half* wrow = wh + ((size_t)p * SS + j) * SS;
    float acc[4] = {0.f, 0.f, 0.f, 0.f};
#pragma unroll 2
    for (int k0 = 0; k0 < SS; k0 += 512) {
        int k = k0 + lane * 8;
        uint4 wv = *(const uint4*)(wrow + k);
        const __half2* wp = (const __half2*)&wv;
#pragma unroll
        for (int b = 0; b < 4; ++b) {
            uint4 hu = *(const uint4*)(hl + b * SS + k);
            const __half2* hp = (const __half2*)&hu;
#pragma unroll
            for (int q = 0; q < 4; ++q)
                acc[b] = fdot2(wp[q], hp[q], acc[b]);
        }
    }
#pragma unroll
    for (int b = 0; b < 4; ++b)
#pragma unroll
        for (int off = 32; off; off >>= 1)
            acc[b] += __shfl_down(acc[b], off);
    if (lane == 0) {
        sm[w][0] = acc[0]; sm[w][1] = acc[1]; sm[w][2] = acc[2]; sm[w][3] = acc[3];
    }
    __syncthreads();
    if (threadIdx.x < 8) {
        int gg = threadIdx.x >> 2, b = threadIdx.x & 3;
        int jj = blockIdx.x * 2 + gg;
        float hr = sm[gg * 3 + 0][b], hz = sm[gg * 3 + 1][b], hn = sm[gg * 3 + 2][b];
        const float* gib = gi + ((size_t)b * TT + t) * G3;
        float r = 1.f / (1.f + expf(-(gib[jj] + hr + b_hh[jj])));
        float z = 1.f / (1.f + expf(-(gib[SS + jj] + hz + b_hh[SS + jj])));
        float nn = tanhf(gib[2 * SS + jj] + r * (hn + b_hh[2 * SS + jj]));
        float hv = (1.f - z) * nn + z * h_in[(size_t)b * SS + jj];
        h_out[(size_t)b * SS + jj] = hv;
        h16_out[(size_t)b * SS + jj] = __float2half(hv);
    }
}

// ---------------------------------------------------------------- GRU step 0: fp32 weights, fused fp16 conversion
__global__ __launch_bounds__(384) void k_gru0(const float* __restrict__ w32,
                                              __half* __restrict__ wh,
                                              const __half* __restrict__ h16_in,
                                              const float* __restrict__ h_in,
                                              const float* __restrict__ b_hh,
                                              const float* __restrict__ gi,
                                              float* __restrict__ h_out,
                                              __half* __restrict__ h16_out) {
    __shared__ __half hl[BB * SS];
    __shared__ float sm[6][4];
    for (int i = threadIdx.x; i < 2048; i += 384)
        *(uint4*)(hl + i * 8) = *(const uint4*)(h16_in + i * 8);
    __syncthreads();

    int w = threadIdx.x >> 6, lane = threadIdx.x & 63;
    int g = (w * 11) >> 5;
    int p = w - g * 3;
    int j = blockIdx.x * 2 + g;
    const float* wrow = w32 + ((size_t)p * SS + j) * SS;
    __half* whrow = wh + ((size_t)p * SS + j) * SS;
    float acc[4] = {0.f, 0.f, 0.f, 0.f};
    for (int k0 = 0; k0 < SS; k0 += 512) {
        int k = k0 + lane * 8;
        float4 fa = *(const float4*)(wrow + k);
        float4 fb = *(const float4*)(wrow + k + 4);
        __half2 wv[4] = {__floats2half2_rn(fa.x, fa.y), __floats2half2_rn(fa.z, fa.w),
                         __floats2half2_rn(fb.x, fb.y), __floats2half2_rn(fb.z, fb.w)};
        *(uint4*)(whrow + k) = *(const uint4*)wv;
#pragma unroll
        for (int b = 0; b < 4; ++b) {
            uint4 hu = *(const uint4*)(hl + b * SS + k);
            const __half2* hp = (const __half2*)&hu;
#pragma unroll
            for (int q = 0; q < 4; ++q)
                acc[b] = fdot2(wv[q], hp[q], acc[b]);
        }
    }
#pragma unroll
    for (int b = 0; b < 4; ++b)
#pragma unroll
        for (int off = 32; off; off >>= 1)
            acc[b] += __shfl_down(acc[b], off);
    if (lane == 0) {
        sm[w][0] = acc[0]; sm[w][1] = acc[1]; sm[w][2] = acc[2]; sm[w][3] = acc[3];
    }
    __syncthreads();
    if (threadIdx.x < 8) {
        int gg = threadIdx.x >> 2, b = threadIdx.x & 3;
        int jj = blockIdx.x * 2 + gg;
        float hr = sm[gg * 3 + 0][b], hz = sm[gg * 3 + 1][b], hn = sm[gg * 3 + 2][b];
        const float* gib = gi + ((size_t)b * TT + 0) * G3;
        float r = 1.f / (1.f + expf(-(gib[jj] + hr + b_hh[jj])));
        float z = 1.f / (1.f + expf(-(gib[SS + jj] + hz + b_hh[SS + jj])));
        float nn = tanhf(gib[2 * SS + jj] + r * (hn + b_hh[2 * SS + jj]));
        float hv = (1.f - z) * nn + z * h_in[(size_t)b * SS + jj];
        h_out[(size_t)b * SS + jj] = hv;
        h16_out[(size_t)b * SS + jj] = __float2half(hv);
    }
}

// ---------------------------------------------------------------- GRU step fp32 (tier C fallback)
__global__ __launch_bounds__(512) void k_gru(const float* __restrict__ w_hh,
                                             const float* __restrict__ b_hh,
                                             const float* __restrict__ gi,
                                             const float* __restrict__ h_in,
                                             float* __restrict__ h_out, int t) {
    __shared__ float hl[BB][SS];
    for (int i = threadIdx.x; i < BB * SS; i += 512)
        hl[i >> 12][i & (SS - 1)] = h_in[i];
    __syncthreads();
    int wave = threadIdx.x >> 6, lane = threadIdx.x & 63;
    int jg = blockIdx.x * 8 + wave;
    const float* r0 = w_hh + (size_t)jg * SS;
    const float* r1 = w_hh + ((size_t)SS + jg) * SS;
    const float* r2 = w_hh + ((size_t)2 * SS + jg) * SS;
    float acc[3][4] = {{0.f}};
    for (int k0 = 0; k0 < SS; k0 += 256) {
        int k = k0 + lane * 4;
        float4 w0 = *(const float4*)(r0 + k);
        float4 w1 = *(const float4*)(r1 + k);
        float4 w2 = *(const float4*)(r2 + k);
#pragma unroll
        for (int b = 0; b < 4; ++b) {
            float4 hv = *(const float4*)&hl[b][k];
            acc[0][b] += w0.x * hv.x + w0.y * hv.y + w0.z * hv.z + w0.w * hv.w;
            acc[1][b] += w1.x * hv.x + w1.y * hv.y + w1.z * hv.z + w1.w * hv.w;
            acc[2][b] += w2.x * hv.x + w2.y * hv.y + w2.z * hv.z + w2.w * hv.w;
        }
    }
#pragma unroll
    for (int p = 0; p < 3; ++p)
#pragma unroll
        for (int b = 0; b < 4; ++b)
#pragma unroll
            for (int off = 32; off; off >>= 1)
                acc[p][b] += __shfl_down(acc[p][b], off);
    if (lane == 0) {
        float br = b_hh[jg], bz = b_hh[SS + jg], bn = b_hh[2 * SS + jg];
#pragma unroll
        for (int b = 0; b < 4; ++b) {
            const float* gib = gi + ((size_t)b * TT + t) * G3;
            float r = 1.f / (1.f + expf(-(gib[jg] + acc[0][b] + br)));
            float z = 1.f / (1.f + expf(-(gib[SS + jg] + acc[1][b] + bz)));
            float nn = tanhf(gib[2 * SS + jg] + r * (acc[2][b] + bn));
            h_out[(size_t)b * SS + jg] = (1.f - z) * nn + z * hl[b][jg];
        }
    }
}

// ---------------------------------------------------------------- support (tier A): sp fp32 + spT fp16 transposed
__global__ __launch_bounds__(256) void k_support2(const float* __restrict__ x,
                                                  const float* __restrict__ h_all,
                                                  const float* __restrict__ invs,
                                                  float* __restrict__ sp,
                                                  __half* __restrict__ spT) {
    int nt = blockIdx.x, b = blockIdx.y, t = blockIdx.z;
    int n0 = nt * 64;
    int o = threadIdx.x & 63, g = threadIdx.x >> 6;
    __shared__ float wl[64][64];
    __shared__ float xl[64][64];
    __shared__ __half tl[64][72];
    for (int i = threadIdx.x; i < 64 * 72 / 2; i += 256)
        *(__half2*)&tl[0][i * 2] = __half2{};
    const float* h = h_all + ((size_t)(t + 1) * BB + b) * SS;
    for (int i = threadIdx.x; i < SS; i += 256) wl[i >> 6][i & 63] = h[i];
    const float* xp = x + ((size_t)(b * TT + t) * NN + n0) * FF;
    for (int i = threadIdx.x; i < 64 * 64; i += 256) {
        int nl = i >> 6, f = i & 63;
        xl[nl][f] = (n0 + nl < NN) ? xp[(size_t)nl * FF + f] : 0.f;
    }
    __syncthreads();
    size_t bt = (size_t)b * TT + t;
    for (int nl = g; nl < 64; nl += 4) {
        int n = n0 + nl;
        if (n >= NN) break;
        float acc = 0.f;
#pragma unroll
        for (int f = 0; f < 64; ++f) acc += xl[nl][f] * wl[f][o];
        size_t idx = bt * NN + n;
        float v = acc * invs[idx];
        sp[idx * OO + o] = v;
        tl[o][nl] = __float2half(v);
    }
    __syncthreads();
    int orow = threadIdx.x >> 2, seg = threadIdx.x & 3;
    uint4 lo = *(const uint4*)&tl[orow][seg * 16];
    uint4 hi = *(const uint4*)&tl[orow][seg * 16 + 8];
    __half* dst = spT + ((bt * 64 + orow) * 1024 + n0 + seg * 16);
    *(uint4*)dst = lo;
    *(uint4*)(dst + 8) = hi;
}

// ---------------------------------------------------------------- support (tier B/C): sp fp32 only
__global__ __launch_bounds__(256) void k_support(const float* __restrict__ x,
                                                 const float* __restrict__ h_all,
                                                 const float* __restrict__ invs,
                                                 float* __restrict__ sp) {
    int nt = blockIdx.x, b = blockIdx.y, t = blockIdx.z;
    int n0 = nt * 64;
    int o = threadIdx.x & 63, g = threadIdx.x >> 6;
    __shared__ float wl[64][64];
    __shared__ float xl[64][64];
    const float* h = h_all + ((size_t)(t + 1) * BB + b) * SS;
    for (int i = threadIdx.x; i < SS; i += 256) wl[i >> 6][i & 63] = h[i];
    const float* xp = x + ((size_t)(b * TT + t) * NN + n0) * FF;
    for (int i = threadIdx.x; i < 64 * 64; i += 256) {
        int nl = i >> 6, f = i & 63;
        xl[nl][f] = (n0 + nl < NN) ? xp[(size_t)nl * FF + f] : 0.f;
    }
    __syncthreads();
    for (int nl = g; nl < 64; nl += 4) {
        int n = n0 + nl;
        if (n >= NN) break;
        float acc = 0.f;
#pragma unroll
        for (int f = 0; f < 64; ++f) acc += xl[nl][f] * wl[f][o];
        size_t idx = ((size_t)(b * TT + t) * NN + n);
        sp[idx * OO + o] = acc * invs[idx];
    }
}

// ---------------------------------------------------------------- k_out MFMA (tier A)
__global__ __launch_bounds__(256) void k_out_mfma(const __half* __restrict__ adjh,
                                                  const __half* __restrict__ spT,
                                                  const float* __restrict__ sp32,
                                                  const float* __restrict__ invs,
                                                  const float* __restrict__ bias,
                                                  float* __restrict__ out) {
    int nb = blockIdx.x, b = blockIdx.y, t = blockIdx.z;
    int n0 = nb * 64;
    size_t bt = (size_t)b * TT + t;
    __shared__ alignas(16) __half Al[64 * 64];
    __shared__ alignas(16) __half Bl[64 * 64];
    int wave = threadIdx.x >> 6, lane = threadIdx.x & 63;
    const __half* Ag = adjh + bt * (size_t)(NN * NN);
    const __half* Bg = spT + bt * (size_t)(64 * 1024);
    f32x4 acc[4] = {};

    for (int ch = 0; ch < 16; ++ch) {
        __syncthreads();
#pragma unroll
        for (int rep = 0; rep < 2; ++rep) {
            int idx = threadIdx.x + rep * 256;
            int r = idx >> 3, g = idx & 7;
            int gg = ch * 8 + g;
            uint4 va = {0, 0, 0, 0};
            if (n0 + r < NN && gg < 125)
                va = *(const uint4*)(Ag + (size_t)(n0 + r) * NN + gg * 8);
            *(uint4*)&Al[(r * 8 + (g ^ (r & 7))) * 8] = va;
            uint4 vb = *(const uint4*)(Bg + (size_t)r * 1024 + gg * 8);
            *(uint4*)&Bl[(r * 8 + (g ^ (r & 7))) * 8] = vb;
        }
        __syncthreads();
#pragma unroll
        for (int kc = 0; kc < 2; ++kc) {
            int ar = wave * 16 + (lane & 15);
            int ag = kc * 4 + (lane >> 4);
            f16x8 av = *(const f16x8*)&Al[(ar * 8 + (ag ^ (ar & 7))) * 8];
#pragma unroll
            for (int ct = 0; ct < 4; ++ct) {
                int br = ct * 16 + (lane & 15);
                f16x8 bv = *(const f16x8*)&Bl[(br * 8 + (ag ^ (br & 7))) * 8];
                acc[ct] = __builtin_amdgcn_mfma_f32_16x16x32_f16(av, bv, acc[ct], 0, 0, 0);
            }
        }
    }
#pragma unroll
    for (int ct = 0; ct < 4; ++ct) {
        int o = ct * 16 + (lane & 15);
        float bo = bias[o];
#pragma unroll
        for (int r = 0; r < 4; ++r) {
            int n = n0 + wave * 16 + (lane >> 4) * 4 + r;
            if (n < NN) {
                float iv = invs[bt * NN + n];
                float d = sp32[(bt * NN + n) * OO + o];
                out[(bt * NN + n) * OO + o] = fmaxf(iv * (acc[ct][r] + d) + bo, 0.f);
            }
        }
    }
}

// ---------------------------------------------------------------- k_out fp32 (tier B/C)
__global__ __launch_bounds__(256) void k_out(const float* __restrict__ adj,
                                             const float* __restrict__ sp,
                                             const float* __restrict__ invs,
                                             const float* __restrict__ bias,
                                             float* __restrict__ out) {
    int nb = blockIdx.x, b = blockIdx.y, t = blockIdx.z;
    int n0 = nb * 64;
    int cq = threadIdx.x & 15;
    int rg = threadIdx.x >> 4;
    __shared__ float spl[64][64];
    __shared__ float al[64][68];
    size_t bt = (size_t)b * TT + t;
    const float* adjp = adj + bt * (size_t)NN * NN;
    const float* spp  = sp  + bt * (size_t)NN * OO;
    float4 a0 = {0,0,0,0}, a1 = {0,0,0,0}, a2 = {0,0,0,0}, a3 = {0,0,0,0};
    for (int m0 = 0; m0 < NN; m0 += 64) {
        __syncthreads();
        for (int i = threadIdx.x; i < 1024; i += 256) {
            int r = i >> 4, c4 = (i & 15) * 4;
            int m = m0 + r;
            float4 v = (m < NN) ? *(const float4*)&spp[(size_t)m * OO + c4] : float4{0,0,0,0};
            *(float4*)&spl[r][c4] = v;
        }
        for (int i = threadIdx.x; i < 1024; i += 256) {
            int r = i >> 4, c4 = (i & 15) * 4;
            int n = n0 + r, m = m0 + c4;
            float4 v = (n < NN && m < NN) ? *(const float4*)&adjp[(size_t)n * NN + m] : float4{0,0,0,0};
            *(float4*)&al[r][c4] = v;
        }
        __syncthreads();
#pragma unroll 4
        for (int mm = 0; mm < 64; mm += 4) {
            float4 s0 = *(const float4*)&spl[mm + 0][cq * 4];
            float4 s1 = *(const float4*)&spl[mm + 1][cq * 4];
            float4 s2 = *(const float4*)&spl[mm + 2][cq * 4];
            float4 s3 = *(const float4*)&spl[mm + 3][cq * 4];
            float4 r0 = *(const float4*)&al[rg * 4 + 0][mm];
            float4 r1 = *(const float4*)&al[rg * 4 + 1][mm];
            float4 r2 = *(const float4*)&al[rg * 4 + 2][mm];
            float4 r3 = *(const float4*)&al[rg * 4 + 3][mm];
            a0.x += r0.x*s0.x + r0.y*s1.x + r0.z*s2.x + r0.w*s3.x;
            a0.y += r0.x*s0.y + r0.y*s1.y + r0.z*s2.y + r0.w*s3.y;
            a0.z += r0.x*s0.z + r0.y*s1.z + r0.z*s2.z + r0.w*s3.z;
            a0.w += r0.x*s0.w + r0.y*s1.w + r0.z*s2.w + r0.w*s3.w;
            a1.x += r1.x*s0.x + r1.y*s1.x + r1.z*s2.x + r1.w*s3.x;
            a1.y += r1.x*s0.y + r1.y*s1.y + r1.z*s2.y + r1.w*s3.y;
            a1.z += r1.x*s0.z + r1.y*s1.z + r1.z*s2.z + r1.w*s3.z;
            a1.w += r1.x*s0.w + r1.y*s1.w + r1.z*s2.w + r1.w*s3.w;
            a2.x += r2.x*s0.x + r2.y*s1.x + r2.z*s2.x + r2.w*s3.x;
            a2.y += r2.x*s0.y + r2.y*s1.y + r2.z*s2.y + r2.w*s3.y;
            a2.z += r2.x*s0.z + r2.y*s1.z + r2.z*s2.z + r2.w*s3.z;
            a2.w += r2.x*s0.w + r2.y*s1.w + r2.z*s2.w + r2.w*s3.w;
            a3.x += r3.x*s0.x + r3.y*s1.x + r3.z*s2.x + r3.w*s3.x;
            a3.y += r3.x*s0.y + r3.y*s1.y + r3.z*s2.y + r3.w*s3.y;
            a3.z += r3.x*s0.z + r3.y*s1.z + r3.z*s2.z + r3.w*s3.z;
            a3.w += r3.x*s0.w + r3.y*s1.w + r3.z*s2.w + r3.w*s3.w;
        }
    }
    float4 bias4 = *(const float4*)&bias[cq * 4];
    float4 accs[4] = {a0, a1, a2, a3};
#pragma unroll
    for (int i = 0; i < 4; ++i) {
        int n = n0 + rg * 4 + i;
        if (n < NN) {
            float iv = invs[bt * NN + n];
            float4 d = *(const float4*)&spp[(size_t)n * OO + cq * 4];
            float4 v;
            v.x = fmaxf(iv * (accs[i].x + d.x) + bias4.x, 0.f);
            v.y = fmaxf(iv * (accs[i].y + d.y) + bias4.y, 0.f);
            v.z = fmaxf(iv * (accs[i].z + d.z) + bias4.z, 0.f);
            v.w = fmaxf(iv * (accs[i].w + d.w) + bias4.w, 0.f);
            *(float4*)&out[(bt * NN + n) * OO + cq * 4] = v;
        }
    }
}

// ---------------------------------------------------------------- launch
extern "C" void kernel_launch(void* const* d_in, const int* in_sizes, int n_in,
                              void* d_out, int out_size, void* d_ws, size_t ws_size,
                              hipStream_t stream) {
    const float* x    = (const float*)d_in[0];
    const float* adj  = (const float*)d_in[1];
    const float* w_ih = (const float*)d_in[2];
    const float* w_hh = (const float*)d_in[3];
    const float* b_ih = (const float*)d_in[4];
    const float* b_hh = (const float*)d_in[5];
    const float* h0   = (const float*)d_in[6];
    const float* bias = (const float*)d_in[7];
    float* out = (float*)d_out;
    float* ws = (float*)d_ws;

    float* invs  = ws;                          // 48000
    float* summ  = invs + 48000;                // 3072
    float* gi    = summ + 3072;                 // 589824
    float* h_all = gi + 589824;                 // 13 * 16384 = 212992
    float* sp    = h_all + 212992;              // 3072000
    const size_t base_f = 3925888;              // floats
    __half* wh    = (__half*)(ws + base_f);         // 50,331,648 halves (100.7 MB)
    __half* h16   = wh + 50331648ull;               // 13 * 16384 halves
    __half* adjh  = h16 + 212992ull;                // 48,000,000 halves (96 MB)
    __half* spT   = adjh + 48000000ull;             // 3,145,728 halves (6.3 MB)
    const size_t need_B = base_f * 4 + (50331648ull + 212992ull) * 2;
    const size_t need_A = need_B + (48000000ull + 3145728ull) * 2;
    bool tierA = ws_size >= need_A;
    bool tierB = ws_size >= need_B;

    k_init_h<<<64, 256, 0, stream>>>(h0, h_all, h16);
    k_summary<<<48, 256, 0, stream>>>(x, summ);
    k_gi<<<dim3(48, 48), 256, 0, stream>>>(summ, w_ih, b_ih, gi);
    if (tierB) {
        k_gru0<<<2048, 384, 0, stream>>>(w_hh, wh, h16, h_all, b_hh, gi,
                                         h_all + (size_t)BB * SS,
                                         h16 + (size_t)BB * SS);
        for (int t = 1; t < TT; ++t)
            k_gruN<<<2048, 384, 0, stream>>>(wh,
                                             h16 + (size_t)t * BB * SS,
                                             h_all + (size_t)t * BB * SS,
                                             b_hh, gi,
                                             h_all + (size_t)(t + 1) * BB * SS,
                                             h16 + (size_t)(t + 1) * BB * SS, t);
    } else {
        for (int t = 0; t < TT; ++t)
            k_gru<<<512, 512, 0, stream>>>(w_hh, b_hh, gi,
                                           h_all + (size_t)t * BB * SS,
                                           h_all + (size_t)(t + 1) * BB * SS, t);
    }
    if (tierA) {
        k_degconv<<<12000, 256, 0, stream>>>(adj, invs, adjh);
        k_support2<<<dim3(16, 4, 12), 256, 0, stream>>>(x, h_all, invs, sp, spT);
        k_out_mfma<<<dim3(16, 4, 12), 256, 0, stream>>>(adjh, spT, sp, invs, bias, out);
    } else {
        k_deg<<<12000, 256, 0, stream>>>(adj, invs);
        k_support<<<dim3(16, 4, 12), 256, 0, stream>>>(x, h_all, invs, sp);
        k_out<<<dim3(32, 4, 12), 256, 0, stream>>>(adj, sp, invs, bias, out);
    }
}